// Round 5
// baseline (162.352 us; speedup 1.0000x reference)
//
#include <hip/hip_runtime.h>
#include <hip/hip_bf16.h>
#include <cmath>

#define BB 2
#define TT 64
#define CC 384
#define HH 768

// d_out flat offsets (fp32 elements): out, nW0, nb0, nW1, nb1
#define O_OUT 0
#define O_NW0 768
#define O_NB0 (768 + 589824)
#define O_NW1 (O_NB0 + 1536)
#define O_NB1 (O_NW1 + 589824)

#define GRID_BLKS 312
#define BAR_MAGIC 0x5F3A9D71u
#define AGT __HIP_MEMORY_SCOPE_AGENT

// barrier words: flag @0; arrive[w][shard] 4x8 lines; departs of last barrier
#define W_ARR(w, s) (32 + ((w) * 8 + (s)) * 32)
#define W_DEP       (32 + 32 * 32)
#define BAR_WORDS   1536

struct Coefs { float ct[TT]; float dfac; };

typedef __attribute__((ext_vector_type(8))) short bf16x8;
typedef __attribute__((ext_vector_type(4))) float f32x4;

__device__ __forceinline__ unsigned short f2bf(float f) {
    union { float f; unsigned int i; } u; u.f = f;
    unsigned int x = u.i;
    unsigned int r = (x + 0x7fffu + ((x >> 16) & 1u)) >> 16;  // RNE
    return (unsigned short)r;
}
__device__ __forceinline__ f32x4 mfma16(bf16x8 a, bf16x8 b, f32x4 c) {
    return __builtin_amdgcn_mfma_f32_16x16x32_bf16(a, b, c, 0, 0, 0);
}
__device__ __forceinline__ bf16x8 ldcvt8(const float* p) {
    float4 a = *(const float4*)p, b = *(const float4*)(p + 4);
    bf16x8 r;
    r[0] = (short)f2bf(a.x); r[1] = (short)f2bf(a.y); r[2] = (short)f2bf(a.z); r[3] = (short)f2bf(a.w);
    r[4] = (short)f2bf(b.x); r[5] = (short)f2bf(b.y); r[6] = (short)f2bf(b.z); r[7] = (short)f2bf(b.w);
    return r;
}

// system-scope write-through store: global_store_dword sc0 sc1 -> visible at the
// cross-XCD coherence point once vmcnt retires; no fence/wbl2 ever needed.
__device__ __forceinline__ void sysst(float* p, float v) {
    __hip_atomic_store(p, v, __ATOMIC_RELAXED, __HIP_MEMORY_SCOPE_SYSTEM);
}
__device__ __forceinline__ unsigned aload(unsigned* p) {
    return __hip_atomic_load(p, __ATOMIC_RELAXED, AGT);
}
__device__ __forceinline__ void aadd(unsigned* p, unsigned v) {
    __hip_atomic_fetch_add(p, v, __ATOMIC_RELAXED, AGT);
}
__device__ __forceinline__ void astore(unsigned* p, unsigned v) {
    __hip_atomic_store(p, v, __ATOMIC_RELAXED, AGT);
}
__device__ __forceinline__ void bar_reset(unsigned* bar) {
    for (int i = 0; i < 32; ++i) astore(bar + 32 + i * 32, 0u);
    astore(bar + W_DEP, 0u);
}

struct KArgs {
    const float *x, *Wq, *bq, *Wk, *bk, *Wv, *bv, *Wo, *bo, *iq;
    const float *sW0, *sb0, *sW1, *sb1;
    float *kb, *h1, *dp;                    // f32 intermediates (sc1-written)
    float *vb, *qb, *hret, *pred, *dsil, *dh1p, *warm;
    unsigned *bar;
    float *out;
    Coefs cf;
};

// Counter-only grid barrier (no cache maintenance): all cross-phase data is
// sc1 write-through, so L2s never hold dirty intermediate lines and readers'
// first-touch cached loads miss to the (correct) L3. __syncthreads drains each
// wave's stores (vmcnt 0) before the leader's arrive-add.
__device__ __forceinline__ void gsync(unsigned* bar, int w, int shard) {
    __syncthreads();
    if (threadIdx.x == 0) {
        if (w == 0) {   // wait for block 0's counter init on fresh/poisoned ws
            while (aload(bar) != BAR_MAGIC) __builtin_amdgcn_s_sleep(1);
        }
        aadd(bar + W_ARR(w, shard), 1u);
        for (;;) {
            unsigned s = 0;
            #pragma unroll
            for (int x = 0; x < 8; ++x) s += aload(bar + W_ARR(w, x));
            if (s == GRID_BLKS) break;
            __builtin_amdgcn_s_sleep(2);
        }
        if (w == 3) {   // last barrier: last departer resets for graph replay
            unsigned old = __hip_atomic_fetch_add(bar + W_DEP, 1u, __ATOMIC_RELAXED, AGT);
            if (old == GRID_BLKS - 1) bar_reset(bar);
        }
    }
    __syncthreads();
}

// ---- shared tile bodies (used by C2 and D) ----
__device__ __forceinline__ void nw1_tile(const KArgs& A, unsigned char* sbuf, int tile, int j) {
    float* a_t = (float*)sbuf;                 // [64][32]
    float* e_t = (float*)(sbuf + 8192);        // [64][64]
    const int b = tile / 144, rem = tile % 144;
    const int c0 = (rem / 12) * 32, h0 = (rem % 12) * 64;
    for (int i = j; i < TT * 32; i += 256) {
        int t = i >> 5, c = i & 31;
        a_t[t * 32 + c] = A.cf.ct[t] * A.dp[((size_t)(b * TT + t)) * CC + c0 + c];
    }
    for (int i = j; i < TT * 64; i += 256) {
        int t = i >> 6, h = i & 63;
        e_t[t * 64 + h] = A.h1[((size_t)(b * TT + t)) * HH + h0 + h];
    }
    __syncthreads();
    const int ci = j & 31, hb = (j >> 5) * 8;
    float acc[8] = {0, 0, 0, 0, 0, 0, 0, 0};
    for (int t = 0; t < TT; ++t) {
        float av = a_t[t * 32 + ci];
        #pragma unroll
        for (int m = 0; m < 8; ++m) acc[m] += av * e_t[t * 64 + hb + m];
    }
    const size_t idx = ((size_t)b * CC + c0 + ci) * HH + h0 + hb;
    const float4* w4 = (const float4*)(A.sW1 + idx);
    float4 wa = w4[0], wb = w4[1];
    float4 o0, o1;
    o0.x = A.cf.dfac * wa.x - acc[0]; o0.y = A.cf.dfac * wa.y - acc[1];
    o0.z = A.cf.dfac * wa.z - acc[2]; o0.w = A.cf.dfac * wa.w - acc[3];
    o1.x = A.cf.dfac * wb.x - acc[4]; o1.y = A.cf.dfac * wb.y - acc[5];
    o1.z = A.cf.dfac * wb.z - acc[6]; o1.w = A.cf.dfac * wb.w - acc[7];
    *(float4*)(A.out + O_NW1 + idx) = o0;
    *(float4*)(A.out + O_NW1 + idx + 4) = o1;
    if (h0 == 0 && j < 32) {
        float s = 0.f;
        for (int t = 0; t < TT; ++t) s += a_t[t * 32 + j];
        A.out[O_NB1 + b * CC + c0 + j] = A.cf.dfac * A.sb1[b * CC + c0 + j] - s;
    }
}

__device__ __forceinline__ void nw0_tile(const KArgs& A, unsigned char* sbuf, int tile, int j) {
    float* a_t = (float*)sbuf;                 // [64][32]
    float* e_t = (float*)(sbuf + 8192);        // [64][64]
    const int b = tile / 144, rem = tile % 144;
    const int h0 = (rem / 6) * 32, c0 = (rem % 6) * 64;
    for (int i = j; i < TT * 32; i += 256) {
        int t = i >> 5, hl = i & 31;
        a_t[t * 32 + hl] = A.dh1p[((size_t)(b * TT + t)) * HH + h0 + hl];
    }
    for (int i = j; i < TT * 64; i += 256) {
        int t = i >> 6, c = i & 63;
        e_t[t * 64 + c] = A.kb[((size_t)(b * TT + t)) * CC + c0 + c];
    }
    __syncthreads();
    const int hi = j & 31, cb = (j >> 5) * 8;
    float acc[8] = {0, 0, 0, 0, 0, 0, 0, 0};
    for (int t = 0; t < TT; ++t) {
        float av = a_t[t * 32 + hi];
        #pragma unroll
        for (int m = 0; m < 8; ++m) acc[m] += av * e_t[t * 64 + cb + m];
    }
    const size_t idx = ((size_t)b * HH + h0 + hi) * CC + c0 + cb;
    const float4* w4 = (const float4*)(A.sW0 + idx);
    float4 wa = w4[0], wb = w4[1];
    float4 o0, o1;
    o0.x = A.cf.dfac * wa.x - acc[0]; o0.y = A.cf.dfac * wa.y - acc[1];
    o0.z = A.cf.dfac * wa.z - acc[2]; o0.w = A.cf.dfac * wa.w - acc[3];
    o1.x = A.cf.dfac * wb.x - acc[4]; o1.y = A.cf.dfac * wb.y - acc[5];
    o1.z = A.cf.dfac * wb.z - acc[6]; o1.w = A.cf.dfac * wb.w - acc[7];
    *(float4*)(A.out + O_NW0 + idx) = o0;
    *(float4*)(A.out + O_NW0 + idx + 4) = o1;
    if (c0 == 0 && j < 32) {
        float s = 0.f;
        for (int t = 0; t < TT; ++t) s += a_t[t * 32 + j];
        A.out[O_NB0 + b * HH + h0 + j] = A.cf.dfac * A.sb0[b * HH + h0 + j] - s;
    }
}

// Single fused kernel, 5 phases / 4 counter-only barriers:
//   A : [x;iq]@[Wk|Wv|Wq]^T (blocks 0..50) + L3-warm of sW0/sW1/Wo (51..311)
//   B : [kb;q]@sW0^T -> h1/dsil/hret           (blocks 0..59)
//   C : [h1;hret]@sW1^T -> dp/pred             (blocks 0..29)
//   C2: dh1p (0..47) + out (48..95) + nW1 tiles 0..215 (96..311)
//   D : nW1 tiles 216..287 + all 288 nW0 tiles (360 tiles, <=2/block)
__global__ void __launch_bounds__(256, 2) fused(KArgs A) {
    __shared__ __align__(16) unsigned char sbuf[25344];
    const int blk = blockIdx.x, j = threadIdx.x;
    const int shard = blk & 7;

    // barrier counter init, gated on magic flag (leader of block 0 only)
    if (blk == 0 && j == 0) {
        if (aload(A.bar) != BAR_MAGIC) {
            bar_reset(A.bar);
            asm volatile("s_waitcnt vmcnt(0)" ::: "memory");  // zeros visible before flag
            astore(A.bar, BAR_MAGIC);
        }
    }

    // ---------------- Phase A ----------------
    if (blk < 51) {
        const int wid = j >> 6, L = j & 63;
        const int w = blk * 4 + wid;
        const int lrow = L & 15, kq = (L >> 4) * 8, quad = L >> 4;
        int mf, npair;
        if (w < 192) { mf = w % 8; npair = w / 8; }
        else         { mf = 8;     npair = 24 + (w - 192); }
        const float* Arow = (mf < 8) ? (A.x + (size_t)(mf * 16 + lrow) * CC) : A.iq;
        const int n0 = npair * 32 + lrow, n1 = n0 + 16;
        const float* B0 = (n0 < CC) ? (A.Wk + (size_t)n0 * CC)
                        : (n0 < 2 * CC) ? (A.Wv + (size_t)(n0 - CC) * CC)
                        : (A.Wq + (size_t)(n0 - 2 * CC) * CC);
        const float* B1 = (n1 < CC) ? (A.Wk + (size_t)n1 * CC)
                        : (n1 < 2 * CC) ? (A.Wv + (size_t)(n1 - CC) * CC)
                        : (A.Wq + (size_t)(n1 - 2 * CC) * CC);
        f32x4 acc0 = {0,0,0,0}, acc1 = {0,0,0,0};
        #pragma unroll 2
        for (int s = 0; s < CC / 32; ++s) {
            int k = s * 32 + kq;
            bf16x8 a = ldcvt8(Arow + k);
            bf16x8 b0 = ldcvt8(B0 + k), b1 = ldcvt8(B1 + k);
            acc0 = mfma16(a, b0, acc0); acc1 = mfma16(a, b1, acc1);
        }
        #pragma unroll
        for (int ni = 0; ni < 2; ++ni) {
            f32x4 acc = ni == 0 ? acc0 : acc1;
            int n = npair * 32 + ni * 16 + lrow;
            if (mf < 8) {
                #pragma unroll
                for (int r = 0; r < 4; ++r) {
                    int m = mf * 16 + quad * 4 + r;
                    float v = acc[r];
                    if (n < CC) sysst(&A.kb[(size_t)m * CC + n], v + A.bk[n]);
                    else        sysst(&A.vb[(size_t)m * CC + (n - CC)], v + A.bv[n - CC]);
                }
            } else if (quad == 0) {
                sysst(&A.qb[n - 2 * CC], acc[0] + A.bq[n - 2 * CC]);
            }
        }
    } else {
        // warm path: stream the FULL sW0 + sW1 + Wo (5.3 MB) into L3
        int t = (blk - 51) * 256 + j;
        float acc = 0.f;
        for (int g = t; g < 331776; g += (GRID_BLKS - 51) * 256) {
            const float4* src; int off;
            if      (g < 147456) { src = (const float4*)A.sW0; off = g; }
            else if (g < 294912) { src = (const float4*)A.sW1; off = g - 147456; }
            else                 { src = (const float4*)A.Wo;  off = g - 294912; }
            float4 v = src[off];
            acc += v.x + v.y + v.z + v.w;
        }
        if (acc != acc) A.warm[0] = acc;   // never taken (finite data); keeps loads live
    }

    gsync(A.bar, 0, shard);

    // ---------------- Phase B ----------------
    if (blk < 60) {
        const int b = blk / 30;
        const int wid = j >> 6, L = j & 63;
        const int w = (blk % 30) * 4 + wid;
        const int mf = w % 5, npair = w / 5;
        const int lrow = L & 15, kq = (L >> 4) * 8, quad = L >> 4;
        const float* Arow = (mf < 4) ? (A.kb + (size_t)(b * TT + mf * 16 + lrow) * CC) : A.qb;
        const int n0 = npair * 32 + lrow;
        const float* B0 = A.sW0 + (size_t)(b * HH + n0) * CC;
        const float* B1 = B0 + 16 * CC;
        f32x4 acc0 = {0,0,0,0}, acc1 = {0,0,0,0};
        #pragma unroll 2
        for (int s = 0; s < CC / 32; ++s) {
            int k = s * 32 + kq;
            bf16x8 a = ldcvt8(Arow + k);
            bf16x8 b0 = ldcvt8(B0 + k), b1 = ldcvt8(B1 + k);
            acc0 = mfma16(a, b0, acc0); acc1 = mfma16(a, b1, acc1);
        }
        #pragma unroll
        for (int ni = 0; ni < 2; ++ni) {
            f32x4 acc = ni == 0 ? acc0 : acc1;
            int n = npair * 32 + ni * 16 + lrow;
            float bias = A.sb0[b * HH + n];
            if (mf < 4) {
                #pragma unroll
                for (int r = 0; r < 4; ++r) {
                    int t = mf * 16 + quad * 4 + r;
                    float pre = acc[r] + bias;
                    float sig = 1.f / (1.f + expf(-pre));
                    size_t idx = (size_t)(b * TT + t) * HH + n;
                    sysst(&A.h1[idx], pre * sig);
                    sysst(&A.dsil[idx], sig * (1.f + pre * (1.f - sig)));
                }
            } else if (quad == 0) {
                float pre = acc[0] + bias;
                float sig = 1.f / (1.f + expf(-pre));
                sysst(&A.hret[b * HH + n], pre * sig);
            }
        }
    }

    gsync(A.bar, 1, shard);

    // ---------------- Phase C ----------------
    if (blk < 30) {
        const int b = blk / 15;
        const int wid = j >> 6, L = j & 63;
        const int w = (blk % 15) * 4 + wid;
        const int mf = w % 5, npair = w / 5;
        const int lrow = L & 15, kq = (L >> 4) * 8, quad = L >> 4;
        const float* Arow = (mf < 4) ? (A.h1 + (size_t)(b * TT + mf * 16 + lrow) * HH)
                                     : (A.hret + (size_t)b * HH);
        const int n0 = npair * 32 + lrow;
        const float* B0 = A.sW1 + (size_t)(b * CC + n0) * HH;
        const float* B1 = B0 + 16 * HH;
        f32x4 acc0 = {0,0,0,0}, acc1 = {0,0,0,0};
        #pragma unroll 2
        for (int s = 0; s < HH / 32; ++s) {
            int k = s * 32 + kq;
            bf16x8 a = ldcvt8(Arow + k);
            bf16x8 b0 = ldcvt8(B0 + k), b1 = ldcvt8(B1 + k);
            acc0 = mfma16(a, b0, acc0); acc1 = mfma16(a, b1, acc1);
        }
        #pragma unroll
        for (int ni = 0; ni < 2; ++ni) {
            f32x4 acc = ni == 0 ? acc0 : acc1;
            int n = npair * 32 + ni * 16 + lrow;
            float bias = A.sb1[b * CC + n];
            if (mf < 4) {
                #pragma unroll
                for (int r = 0; r < 4; ++r) {
                    int t = mf * 16 + quad * 4 + r;
                    size_t idx = (size_t)(b * TT + t) * CC + n;
                    sysst(&A.dp[idx], acc[r] + bias - A.vb[idx]);
                }
            } else if (quad == 0) {
                sysst(&A.pred[b * CC + n], acc[0] + bias);
            }
        }
    }

    gsync(A.bar, 2, shard);

    // ---------------- Phase C2: dh1p + out + 216 nW1 tiles ----------------
    if (blk < 48) {
        // dh1p[b,t,h] = ct[t] * dsil[b,t,h] * (dp @ sW1[b,:,h]) for h in [h0,h0+32)
        unsigned short* ldsT = (unsigned short*)sbuf;        // [384][33] bf16: [c][hl]
        const int b = blk / 24, h0 = (blk % 24) * 32;
        {
            const int hl = j & 31, cs = j >> 5;               // 8 c-rows per pass
            const float* base = A.sW1 + (size_t)b * CC * HH + h0 + hl;
            for (int c = cs; c < CC; c += 8)
                ldsT[c * 33 + hl] = f2bf(base[(size_t)c * HH]);
        }
        __syncthreads();
        const int wid = j >> 6, L = j & 63;
        const int lrow = L & 15, kq = (L >> 4) * 8, quad = L >> 4;
        const float* Arow = A.dp + (size_t)(b * TT + wid * 16 + lrow) * CC;
        f32x4 acc0 = {0,0,0,0}, acc1 = {0,0,0,0};
        for (int s = 0; s < CC / 32; ++s) {
            int k = s * 32 + kq;
            bf16x8 a = ldcvt8(Arow + k);
            bf16x8 b0, b1;
            #pragma unroll
            for (int i = 0; i < 8; ++i) {
                b0[i] = (short)ldsT[(k + i) * 33 + lrow];
                b1[i] = (short)ldsT[(k + i) * 33 + 16 + lrow];
            }
            acc0 = mfma16(a, b0, acc0); acc1 = mfma16(a, b1, acc1);
        }
        #pragma unroll
        for (int ni = 0; ni < 2; ++ni) {
            f32x4 acc = ni == 0 ? acc0 : acc1;
            int hl = ni * 16 + lrow;
            #pragma unroll
            for (int r = 0; r < 4; ++r) {
                int t = wid * 16 + quad * 4 + r;
                float ds = A.dsil[(size_t)(b * TT + t) * HH + h0 + hl];
                sysst(&A.dh1p[(size_t)(b * TT + t) * HH + h0 + hl], A.cf.ct[t] * (acc[r] * ds));
            }
        }
    } else if (blk < 96) {                // out = pred@Wo^T + bo
        float* vecs = (float*)sbuf;
        float* part = (float*)(sbuf + 4096);
        const int rb = blk - 48;
        const int b = rb / 24, nt = rb % 24;
        if (j < CC / 4) ((float4*)vecs)[j] = ((const float4*)(A.pred + b * CC))[j];
        __syncthreads();
        const int nl = j & 15, ks = j >> 4;
        const int n = nt * 16 + nl;
        const float4* wr = (const float4*)(A.Wo + (size_t)n * CC + ks * 24);
        float s = 0.f;
        #pragma unroll
        for (int i = 0; i < 6; ++i) {
            float4 a4 = wr[i];
            const float* v = vecs + ks * 24 + i * 4;
            s += a4.x * v[0] + a4.y * v[1] + a4.z * v[2] + a4.w * v[3];
        }
        part[ks * 17 + nl] = s;
        __syncthreads();
        if (j < 16) {
            int n2 = nt * 16 + j;
            float acc = A.bo[n2];
            #pragma unroll
            for (int kk = 0; kk < 16; ++kk) acc += part[kk * 17 + j];
            A.out[O_OUT + b * CC + n2] = acc;
        }
    } else {                              // nW1 tiles 0..215 (need only dp,h1: ready)
        nw1_tile(A, sbuf, blk - 96, j);
    }

    gsync(A.bar, 3, shard);

    // ---------------- Phase D: 72 nW1 + 288 nW0 tiles (360), <=2 per block ----------------
    for (int pass = 0; pass < 2; ++pass) {
        int td = blk + pass * GRID_BLKS;
        if (td >= 360) break;
        __syncthreads();   // protect LDS reuse (uniform: all threads share blk)
        if (td < 72) nw1_tile(A, sbuf, 216 + td, j);
        else         nw0_tile(A, sbuf, td - 72, j);
    }
}

extern "C" void kernel_launch(void* const* d_in, const int* in_sizes, int n_in,
                              void* d_out, int out_size, void* d_ws, size_t ws_size,
                              hipStream_t stream) {
    KArgs a;
    a.x   = (const float*)d_in[0];
    a.Wq  = (const float*)d_in[1];
    a.bq  = (const float*)d_in[2];
    a.Wk  = (const float*)d_in[3];
    a.bk  = (const float*)d_in[4];
    a.Wv  = (const float*)d_in[5];
    a.bv  = (const float*)d_in[6];
    a.Wo  = (const float*)d_in[7];
    a.bo  = (const float*)d_in[8];
    a.iq  = (const float*)d_in[9];
    a.sW0 = (const float*)d_in[10];
    a.sb0 = (const float*)d_in[11];
    a.sW1 = (const float*)d_in[12];
    a.sb1 = (const float*)d_in[13];

    // ws layout: [0, 6KB) barrier state, then f32 buffers
    a.bar  = (unsigned*)d_ws;
    float* fw = (float*)d_ws + BAR_WORDS;
    a.qb   = fw;                 // 384
    a.hret = a.qb + 384;         // 1536
    a.pred = a.hret + 1536;      // 768
    a.vb   = a.pred + 768;       // 49152
    a.dsil = a.vb + 49152;       // 98304
    a.warm = a.dsil + 98304;     // 4 (sink, never written in practice)
    a.kb   = a.warm + 4;         // 49152
    a.h1   = a.kb + 49152;       // 98304
    a.dp   = a.h1 + 98304;       // 49152
    a.dh1p = a.dp + 49152;       // 98304

    a.out = (float*)d_out;

    // Closed-form scan coefficients (exact: the clipped seed gate cancels).
    const double mom = 0.9, decay = 1.0 - 0.001, lr = 0.01;
    for (int s = 0; s < TT; ++s) {
        double sum = 0.0;
        for (int t = s; t < TT; ++t) sum += pow(decay, (double)(TT - 1 - t)) * pow(mom, (double)(t - s));
        a.cf.ct[s] = (float)(lr * (1.0 - mom) * sum);
    }
    a.cf.dfac = (float)pow(decay, (double)TT);

    fused<<<dim3(GRID_BLKS), dim3(256), 0, stream>>>(a);
}

// Round 6
// 156.102 us; speedup vs baseline: 1.0400x; 1.0400x over previous
//
#include <hip/hip_runtime.h>
#include <hip/hip_bf16.h>
#include <cmath>

#define BB 2
#define TT 64
#define CC 384
#define HH 768

// d_out flat offsets (fp32 elements): out, nW0, nb0, nW1, nb1
#define O_OUT 0
#define O_NW0 768
#define O_NB0 (768 + 589824)
#define O_NW1 (O_NB0 + 1536)
#define O_NB1 (O_NW1 + 589824)

#define GRID_BLKS 312
#define BAR_MAGIC 0x5F3A9D71u
#define AGT __HIP_MEMORY_SCOPE_AGENT

// barrier lines (32 words = 128 B each): magic @0; arrive[4][8]; done[4][8]; dep; claim[8]
#define L_ARR(w, s)  ((1 + (w) * 8 + (s)) * 32)
#define L_DONE(w, x) ((33 + (w) * 8 + (x)) * 32)
#define L_DEP        (65 * 32)
#define L_CLAIM(x)   ((66 + (x)) * 32)
#define BAR_WORDS    (80 * 32)

struct Coefs { float ct[TT]; float dfac; };

typedef __attribute__((ext_vector_type(8))) short bf16x8;
typedef __attribute__((ext_vector_type(4))) float f32x4;

__device__ __forceinline__ unsigned short f2bf(float f) {
    union { float f; unsigned int i; } u; u.f = f;
    unsigned int x = u.i;
    unsigned int r = (x + 0x7fffu + ((x >> 16) & 1u)) >> 16;  // RNE
    return (unsigned short)r;
}
__device__ __forceinline__ f32x4 mfma16(bf16x8 a, bf16x8 b, f32x4 c) {
    return __builtin_amdgcn_mfma_f32_16x16x32_bf16(a, b, c, 0, 0, 0);
}
__device__ __forceinline__ bf16x8 ldcvt8(const float* p) {
    float4 a = *(const float4*)p, b = *(const float4*)(p + 4);
    bf16x8 r;
    r[0] = (short)f2bf(a.x); r[1] = (short)f2bf(a.y); r[2] = (short)f2bf(a.z); r[3] = (short)f2bf(a.w);
    r[4] = (short)f2bf(b.x); r[5] = (short)f2bf(b.y); r[6] = (short)f2bf(b.z); r[7] = (short)f2bf(b.w);
    return r;
}

// system-scope write-through store: reaches the cross-XCD coherence point when
// vmcnt retires; no fence/wbl2/inv ever needed (validated round 5).
__device__ __forceinline__ void sysst(float* p, float v) {
    __hip_atomic_store(p, v, __ATOMIC_RELAXED, __HIP_MEMORY_SCOPE_SYSTEM);
}
__device__ __forceinline__ unsigned aload(unsigned* p) {
    return __hip_atomic_load(p, __ATOMIC_RELAXED, AGT);
}
__device__ __forceinline__ void aadd(unsigned* p, unsigned v) {
    __hip_atomic_fetch_add(p, v, __ATOMIC_RELAXED, AGT);
}
__device__ __forceinline__ void astore(unsigned* p, unsigned v) {
    __hip_atomic_store(p, v, __ATOMIC_RELAXED, AGT);
}
__device__ __forceinline__ void bar_reset(unsigned* bar) {
    for (int i = 1; i < 74; ++i) astore(bar + i * 32, 0u);   // arrive, done, dep, claims
}

struct KArgs {
    const float *x, *Wq, *bq, *Wk, *bk, *Wv, *bv, *Wo, *bo, *iq;
    const float *sW0, *sb0, *sW1, *sb1;
    float *kb, *h1, *dp;                    // f32 intermediates (sc1-written)
    float *vb, *qb, *hret, *pred, *dsil, *dh1p, *warm;
    unsigned *bar;
    float *out;
    Coefs cf;
};

// Two-tier grid barrier, engineered for LOW POLL PRESSURE on the L3:
//  - arrivals: relaxed adds sharded over 8 lines (~39 RMW/line, pipelined)
//  - tier 1: 8 janitors (one per XCD, CAS-elected at barrier 0) poll the 8
//    arrive shards at fine grain (8 pollers total -> negligible traffic)
//  - tier 2: each janitor writes its XCD's done flag; the other ~304 leaders
//    poll ONLY their own XCD's done line with s_sleep(4) -> ~1 req / 23 cy
//    per line, ~10x below the congestion regime that cost rounds 2-5 ~50 us.
//  - no cache maintenance anywhere: cross-phase data is sc1 write-through.
__device__ __forceinline__ void gsync(unsigned* bar, int w, int shard, bool& jan, int xcc) {
    __syncthreads();
    if (threadIdx.x == 0) {
        if (w == 0) {   // init-gate + janitor election (once per launch)
            while (aload(bar) != BAR_MAGIC) __builtin_amdgcn_s_sleep(8);
            unsigned prev = atomicCAS(bar + L_CLAIM(xcc), 0u, 1u);
            jan = (prev == 0);
        }
        aadd(bar + L_ARR(w, shard), 1u);
        if (jan) {
            for (;;) {
                unsigned s = 0;
                #pragma unroll
                for (int q = 0; q < 8; ++q) s += aload(bar + L_ARR(w, q));
                if (s == GRID_BLKS) break;
                __builtin_amdgcn_s_sleep(2);
            }
            astore(bar + L_DONE(w, xcc), 1u);
        }
        while (aload(bar + L_DONE(w, xcc)) == 0) __builtin_amdgcn_s_sleep(4);
        if (w == 3) {   // last barrier: last departer resets all counters for replay
            unsigned old = __hip_atomic_fetch_add(bar + L_DEP, 1u, __ATOMIC_RELAXED, AGT);
            if (old == GRID_BLKS - 1) bar_reset(bar);
        }
    }
    __syncthreads();
}

// ---- shared tile bodies (used by C2 and D) ----
__device__ __forceinline__ void nw1_tile(const KArgs& A, unsigned char* sbuf, int tile, int j) {
    float* a_t = (float*)sbuf;                 // [64][32]
    float* e_t = (float*)(sbuf + 8192);        // [64][64]
    const int b = tile / 144, rem = tile % 144;
    const int c0 = (rem / 12) * 32, h0 = (rem % 12) * 64;
    for (int i = j; i < TT * 32; i += 256) {
        int t = i >> 5, c = i & 31;
        a_t[t * 32 + c] = A.cf.ct[t] * A.dp[((size_t)(b * TT + t)) * CC + c0 + c];
    }
    for (int i = j; i < TT * 64; i += 256) {
        int t = i >> 6, h = i & 63;
        e_t[t * 64 + h] = A.h1[((size_t)(b * TT + t)) * HH + h0 + h];
    }
    __syncthreads();
    const int ci = j & 31, hb = (j >> 5) * 8;
    float acc[8] = {0, 0, 0, 0, 0, 0, 0, 0};
    for (int t = 0; t < TT; ++t) {
        float av = a_t[t * 32 + ci];
        #pragma unroll
        for (int m = 0; m < 8; ++m) acc[m] += av * e_t[t * 64 + hb + m];
    }
    const size_t idx = ((size_t)b * CC + c0 + ci) * HH + h0 + hb;
    const float4* w4 = (const float4*)(A.sW1 + idx);
    float4 wa = w4[0], wb = w4[1];
    float4 o0, o1;
    o0.x = A.cf.dfac * wa.x - acc[0]; o0.y = A.cf.dfac * wa.y - acc[1];
    o0.z = A.cf.dfac * wa.z - acc[2]; o0.w = A.cf.dfac * wa.w - acc[3];
    o1.x = A.cf.dfac * wb.x - acc[4]; o1.y = A.cf.dfac * wb.y - acc[5];
    o1.z = A.cf.dfac * wb.z - acc[6]; o1.w = A.cf.dfac * wb.w - acc[7];
    *(float4*)(A.out + O_NW1 + idx) = o0;
    *(float4*)(A.out + O_NW1 + idx + 4) = o1;
    if (h0 == 0 && j < 32) {
        float s = 0.f;
        for (int t = 0; t < TT; ++t) s += a_t[t * 32 + j];
        A.out[O_NB1 + b * CC + c0 + j] = A.cf.dfac * A.sb1[b * CC + c0 + j] - s;
    }
}

__device__ __forceinline__ void nw0_tile(const KArgs& A, unsigned char* sbuf, int tile, int j) {
    float* a_t = (float*)sbuf;                 // [64][32]
    float* e_t = (float*)(sbuf + 8192);        // [64][64]
    const int b = tile / 144, rem = tile % 144;
    const int h0 = (rem / 6) * 32, c0 = (rem % 6) * 64;
    for (int i = j; i < TT * 32; i += 256) {
        int t = i >> 5, hl = i & 31;
        a_t[t * 32 + hl] = A.dh1p[((size_t)(b * TT + t)) * HH + h0 + hl];
    }
    for (int i = j; i < TT * 64; i += 256) {
        int t = i >> 6, c = i & 63;
        e_t[t * 64 + c] = A.kb[((size_t)(b * TT + t)) * CC + c0 + c];
    }
    __syncthreads();
    const int hi = j & 31, cb = (j >> 5) * 8;
    float acc[8] = {0, 0, 0, 0, 0, 0, 0, 0};
    for (int t = 0; t < TT; ++t) {
        float av = a_t[t * 32 + hi];
        #pragma unroll
        for (int m = 0; m < 8; ++m) acc[m] += av * e_t[t * 64 + cb + m];
    }
    const size_t idx = ((size_t)b * HH + h0 + hi) * CC + c0 + cb;
    const float4* w4 = (const float4*)(A.sW0 + idx);
    float4 wa = w4[0], wb = w4[1];
    float4 o0, o1;
    o0.x = A.cf.dfac * wa.x - acc[0]; o0.y = A.cf.dfac * wa.y - acc[1];
    o0.z = A.cf.dfac * wa.z - acc[2]; o0.w = A.cf.dfac * wa.w - acc[3];
    o1.x = A.cf.dfac * wb.x - acc[4]; o1.y = A.cf.dfac * wb.y - acc[5];
    o1.z = A.cf.dfac * wb.z - acc[6]; o1.w = A.cf.dfac * wb.w - acc[7];
    *(float4*)(A.out + O_NW0 + idx) = o0;
    *(float4*)(A.out + O_NW0 + idx + 4) = o1;
    if (c0 == 0 && j < 32) {
        float s = 0.f;
        for (int t = 0; t < TT; ++t) s += a_t[t * 32 + j];
        A.out[O_NB0 + b * HH + h0 + j] = A.cf.dfac * A.sb0[b * HH + h0 + j] - s;
    }
}

// Single fused kernel, 5 phases / 4 two-tier barriers:
//   A : [x;iq]@[Wk|Wv|Wq]^T (blocks 0..50) + L3-warm of sW0/sW1/Wo (51..311)
//   B : [kb;q]@sW0^T -> h1/dsil/hret           (blocks 0..59)
//   C : [h1;hret]@sW1^T -> dp/pred             (blocks 0..29)
//   C2: dh1p (0..47) + out (48..95) + nW1 tiles 0..215 (96..311)
//   D : nW1 tiles 216..287 + all 288 nW0 tiles (360 tiles, <=2/block)
__global__ void __launch_bounds__(256, 2) fused(KArgs A) {
    __shared__ __align__(16) unsigned char sbuf[25344];
    const int blk = blockIdx.x, j = threadIdx.x;
    const int shard = blk & 7;
    bool jan = false;
    int xcc;
    asm volatile("s_getreg_b32 %0, hwreg(HW_REG_XCC_ID)" : "=s"(xcc));
    xcc &= 7;

    // barrier state init, gated on magic flag (leader of block 0 only)
    if (blk == 0 && j == 0) {
        if (aload(A.bar) != BAR_MAGIC) {
            bar_reset(A.bar);
            asm volatile("s_waitcnt vmcnt(0)" ::: "memory");  // zeros visible before flag
            astore(A.bar, BAR_MAGIC);
        }
    }

    // ---------------- Phase A ----------------
    if (blk < 51) {
        const int wid = j >> 6, L = j & 63;
        const int w = blk * 4 + wid;
        const int lrow = L & 15, kq = (L >> 4) * 8, quad = L >> 4;
        int mf, npair;
        if (w < 192) { mf = w % 8; npair = w / 8; }
        else         { mf = 8;     npair = 24 + (w - 192); }
        const float* Arow = (mf < 8) ? (A.x + (size_t)(mf * 16 + lrow) * CC) : A.iq;
        const int n0 = npair * 32 + lrow, n1 = n0 + 16;
        const float* B0 = (n0 < CC) ? (A.Wk + (size_t)n0 * CC)
                        : (n0 < 2 * CC) ? (A.Wv + (size_t)(n0 - CC) * CC)
                        : (A.Wq + (size_t)(n0 - 2 * CC) * CC);
        const float* B1 = (n1 < CC) ? (A.Wk + (size_t)n1 * CC)
                        : (n1 < 2 * CC) ? (A.Wv + (size_t)(n1 - CC) * CC)
                        : (A.Wq + (size_t)(n1 - 2 * CC) * CC);
        f32x4 acc0 = {0,0,0,0}, acc1 = {0,0,0,0};
        #pragma unroll 2
        for (int s = 0; s < CC / 32; ++s) {
            int k = s * 32 + kq;
            bf16x8 a = ldcvt8(Arow + k);
            bf16x8 b0 = ldcvt8(B0 + k), b1 = ldcvt8(B1 + k);
            acc0 = mfma16(a, b0, acc0); acc1 = mfma16(a, b1, acc1);
        }
        #pragma unroll
        for (int ni = 0; ni < 2; ++ni) {
            f32x4 acc = ni == 0 ? acc0 : acc1;
            int n = npair * 32 + ni * 16 + lrow;
            if (mf < 8) {
                #pragma unroll
                for (int r = 0; r < 4; ++r) {
                    int m = mf * 16 + quad * 4 + r;
                    float v = acc[r];
                    if (n < CC) sysst(&A.kb[(size_t)m * CC + n], v + A.bk[n]);
                    else        sysst(&A.vb[(size_t)m * CC + (n - CC)], v + A.bv[n - CC]);
                }
            } else if (quad == 0) {
                sysst(&A.qb[n - 2 * CC], acc[0] + A.bq[n - 2 * CC]);
            }
        }
    } else {
        // warm path: stream the FULL sW0 + sW1 + Wo (5.3 MB) into L3
        int t = (blk - 51) * 256 + j;
        float acc = 0.f;
        for (int g = t; g < 331776; g += (GRID_BLKS - 51) * 256) {
            const float4* src; int off;
            if      (g < 147456) { src = (const float4*)A.sW0; off = g; }
            else if (g < 294912) { src = (const float4*)A.sW1; off = g - 147456; }
            else                 { src = (const float4*)A.Wo;  off = g - 294912; }
            float4 v = src[off];
            acc += v.x + v.y + v.z + v.w;
        }
        if (acc != acc) A.warm[0] = acc;   // never taken (finite data); keeps loads live
    }

    gsync(A.bar, 0, shard, jan, xcc);

    // ---------------- Phase B ----------------
    if (blk < 60) {
        const int b = blk / 30;
        const int wid = j >> 6, L = j & 63;
        const int w = (blk % 30) * 4 + wid;
        const int mf = w % 5, npair = w / 5;
        const int lrow = L & 15, kq = (L >> 4) * 8, quad = L >> 4;
        const float* Arow = (mf < 4) ? (A.kb + (size_t)(b * TT + mf * 16 + lrow) * CC) : A.qb;
        const int n0 = npair * 32 + lrow;
        const float* B0 = A.sW0 + (size_t)(b * HH + n0) * CC;
        const float* B1 = B0 + 16 * CC;
        f32x4 acc0 = {0,0,0,0}, acc1 = {0,0,0,0};
        #pragma unroll 2
        for (int s = 0; s < CC / 32; ++s) {
            int k = s * 32 + kq;
            bf16x8 a = ldcvt8(Arow + k);
            bf16x8 b0 = ldcvt8(B0 + k), b1 = ldcvt8(B1 + k);
            acc0 = mfma16(a, b0, acc0); acc1 = mfma16(a, b1, acc1);
        }
        #pragma unroll
        for (int ni = 0; ni < 2; ++ni) {
            f32x4 acc = ni == 0 ? acc0 : acc1;
            int n = npair * 32 + ni * 16 + lrow;
            float bias = A.sb0[b * HH + n];
            if (mf < 4) {
                #pragma unroll
                for (int r = 0; r < 4; ++r) {
                    int t = mf * 16 + quad * 4 + r;
                    float pre = acc[r] + bias;
                    float sig = 1.f / (1.f + expf(-pre));
                    size_t idx = (size_t)(b * TT + t) * HH + n;
                    sysst(&A.h1[idx], pre * sig);
                    sysst(&A.dsil[idx], sig * (1.f + pre * (1.f - sig)));
                }
            } else if (quad == 0) {
                float pre = acc[0] + bias;
                float sig = 1.f / (1.f + expf(-pre));
                sysst(&A.hret[b * HH + n], pre * sig);
            }
        }
    }

    gsync(A.bar, 1, shard, jan, xcc);

    // ---------------- Phase C ----------------
    if (blk < 30) {
        const int b = blk / 15;
        const int wid = j >> 6, L = j & 63;
        const int w = (blk % 15) * 4 + wid;
        const int mf = w % 5, npair = w / 5;
        const int lrow = L & 15, kq = (L >> 4) * 8, quad = L >> 4;
        const float* Arow = (mf < 4) ? (A.h1 + (size_t)(b * TT + mf * 16 + lrow) * HH)
                                     : (A.hret + (size_t)b * HH);
        const int n0 = npair * 32 + lrow;
        const float* B0 = A.sW1 + (size_t)(b * CC + n0) * HH;
        const float* B1 = B0 + 16 * HH;
        f32x4 acc0 = {0,0,0,0}, acc1 = {0,0,0,0};
        #pragma unroll 2
        for (int s = 0; s < HH / 32; ++s) {
            int k = s * 32 + kq;
            bf16x8 a = ldcvt8(Arow + k);
            bf16x8 b0 = ldcvt8(B0 + k), b1 = ldcvt8(B1 + k);
            acc0 = mfma16(a, b0, acc0); acc1 = mfma16(a, b1, acc1);
        }
        #pragma unroll
        for (int ni = 0; ni < 2; ++ni) {
            f32x4 acc = ni == 0 ? acc0 : acc1;
            int n = npair * 32 + ni * 16 + lrow;
            float bias = A.sb1[b * CC + n];
            if (mf < 4) {
                #pragma unroll
                for (int r = 0; r < 4; ++r) {
                    int t = mf * 16 + quad * 4 + r;
                    size_t idx = (size_t)(b * TT + t) * CC + n;
                    sysst(&A.dp[idx], acc[r] + bias - A.vb[idx]);
                }
            } else if (quad == 0) {
                sysst(&A.pred[b * CC + n], acc[0] + bias);
            }
        }
    }

    gsync(A.bar, 2, shard, jan, xcc);

    // ---------------- Phase C2: dh1p + out + 216 nW1 tiles ----------------
    if (blk < 48) {
        // dh1p[b,t,h] = ct[t] * dsil[b,t,h] * (dp @ sW1[b,:,h]) for h in [h0,h0+32)
        unsigned short* ldsT = (unsigned short*)sbuf;        // [384][33] bf16: [c][hl]
        const int b = blk / 24, h0 = (blk % 24) * 32;
        {
            const int hl = j & 31, cs = j >> 5;               // 8 c-rows per pass
            const float* base = A.sW1 + (size_t)b * CC * HH + h0 + hl;
            for (int c = cs; c < CC; c += 8)
                ldsT[c * 33 + hl] = f2bf(base[(size_t)c * HH]);
        }
        __syncthreads();
        const int wid = j >> 6, L = j & 63;
        const int lrow = L & 15, kq = (L >> 4) * 8, quad = L >> 4;
        const float* Arow = A.dp + (size_t)(b * TT + wid * 16 + lrow) * CC;
        f32x4 acc0 = {0,0,0,0}, acc1 = {0,0,0,0};
        for (int s = 0; s < CC / 32; ++s) {
            int k = s * 32 + kq;
            bf16x8 a = ldcvt8(Arow + k);
            bf16x8 b0, b1;
            #pragma unroll
            for (int i = 0; i < 8; ++i) {
                b0[i] = (short)ldsT[(k + i) * 33 + lrow];
                b1[i] = (short)ldsT[(k + i) * 33 + 16 + lrow];
            }
            acc0 = mfma16(a, b0, acc0); acc1 = mfma16(a, b1, acc1);
        }
        #pragma unroll
        for (int ni = 0; ni < 2; ++ni) {
            f32x4 acc = ni == 0 ? acc0 : acc1;
            int hl = ni * 16 + lrow;
            #pragma unroll
            for (int r = 0; r < 4; ++r) {
                int t = wid * 16 + quad * 4 + r;
                float ds = A.dsil[(size_t)(b * TT + t) * HH + h0 + hl];
                sysst(&A.dh1p[(size_t)(b * TT + t) * HH + h0 + hl], A.cf.ct[t] * (acc[r] * ds));
            }
        }
    } else if (blk < 96) {                // out = pred@Wo^T + bo
        float* vecs = (float*)sbuf;
        float* part = (float*)(sbuf + 4096);
        const int rb = blk - 48;
        const int b = rb / 24, nt = rb % 24;
        if (j < CC / 4) ((float4*)vecs)[j] = ((const float4*)(A.pred + b * CC))[j];
        __syncthreads();
        const int nl = j & 15, ks = j >> 4;
        const int n = nt * 16 + nl;
        const float4* wr = (const float4*)(A.Wo + (size_t)n * CC + ks * 24);
        float s = 0.f;
        #pragma unroll
        for (int i = 0; i < 6; ++i) {
            float4 a4 = wr[i];
            const float* v = vecs + ks * 24 + i * 4;
            s += a4.x * v[0] + a4.y * v[1] + a4.z * v[2] + a4.w * v[3];
        }
        part[ks * 17 + nl] = s;
        __syncthreads();
        if (j < 16) {
            int n2 = nt * 16 + j;
            float acc = A.bo[n2];
            #pragma unroll
            for (int kk = 0; kk < 16; ++kk) acc += part[kk * 17 + j];
            A.out[O_OUT + b * CC + n2] = acc;
        }
    } else {                              // nW1 tiles 0..215 (need only dp,h1: ready)
        nw1_tile(A, sbuf, blk - 96, j);
    }

    gsync(A.bar, 3, shard, jan, xcc);

    // ---------------- Phase D: 72 nW1 + 288 nW0 tiles (360), <=2 per block ----------------
    for (int pass = 0; pass < 2; ++pass) {
        int td = blk + pass * GRID_BLKS;
        if (td >= 360) break;
        __syncthreads();   // protect LDS reuse (uniform: all threads share blk)
        if (td < 72) nw1_tile(A, sbuf, 216 + td, j);
        else         nw0_tile(A, sbuf, td - 72, j);
    }
}

extern "C" void kernel_launch(void* const* d_in, const int* in_sizes, int n_in,
                              void* d_out, int out_size, void* d_ws, size_t ws_size,
                              hipStream_t stream) {
    KArgs a;
    a.x   = (const float*)d_in[0];
    a.Wq  = (const float*)d_in[1];
    a.bq  = (const float*)d_in[2];
    a.Wk  = (const float*)d_in[3];
    a.bk  = (const float*)d_in[4];
    a.Wv  = (const float*)d_in[5];
    a.bv  = (const float*)d_in[6];
    a.Wo  = (const float*)d_in[7];
    a.bo  = (const float*)d_in[8];
    a.iq  = (const float*)d_in[9];
    a.sW0 = (const float*)d_in[10];
    a.sb0 = (const float*)d_in[11];
    a.sW1 = (const float*)d_in[12];
    a.sb1 = (const float*)d_in[13];

    // ws layout: [0, 10KB) barrier state, then f32 buffers
    a.bar  = (unsigned*)d_ws;
    float* fw = (float*)d_ws + BAR_WORDS;
    a.qb   = fw;                 // 384
    a.hret = a.qb + 384;         // 1536
    a.pred = a.hret + 1536;      // 768
    a.vb   = a.pred + 768;       // 49152
    a.dsil = a.vb + 49152;       // 98304
    a.warm = a.dsil + 98304;     // 4 (sink, never written in practice)
    a.kb   = a.warm + 4;         // 49152
    a.h1   = a.kb + 49152;       // 98304
    a.dp   = a.h1 + 98304;       // 49152
    a.dh1p = a.dp + 49152;       // 98304

    a.out = (float*)d_out;

    // Closed-form scan coefficients (exact: the clipped seed gate cancels).
    const double mom = 0.9, decay = 1.0 - 0.001, lr = 0.01;
    for (int s = 0; s < TT; ++s) {
        double sum = 0.0;
        for (int t = s; t < TT; ++t) sum += pow(decay, (double)(TT - 1 - t)) * pow(mom, (double)(t - s));
        a.cf.ct[s] = (float)(lr * (1.0 - mom) * sum);
    }
    a.cf.dfac = (float)pow(decay, (double)TT);

    fused<<<dim3(GRID_BLKS), dim3(256), 0, stream>>>(a);
}

// Round 8
// 152.552 us; speedup vs baseline: 1.0642x; 1.0233x over previous
//
#include <hip/hip_runtime.h>
#include <hip/hip_bf16.h>
#include <cmath>

#define BB 2
#define TT 64
#define CC 384
#define HH 768

// d_out flat offsets (fp32 elements): out, nW0, nb0, nW1, nb1
#define O_OUT 0
#define O_NW0 768
#define O_NB0 (768 + 589824)
#define O_NW1 (O_NB0 + 1536)
#define O_NB1 (O_NW1 + 589824)

#define GRID_BLKS 312
#define BAR_MAGIC 0x5F3A9D71u
#define AGT __HIP_MEMORY_SCOPE_AGENT

// barrier lines (32 words = 128 B each): magic @0; arrive[4][8]; done[4][8]; dep; claim[8]
#define L_ARR(w, s)  ((1 + (w) * 8 + (s)) * 32)
#define L_DONE(w, x) ((33 + (w) * 8 + (x)) * 32)
#define L_DEP        (65 * 32)
#define L_CLAIM(x)   ((66 + (x)) * 32)
#define BAR_WORDS    (80 * 32)

struct Coefs { float ct[TT]; float dfac; };

typedef __attribute__((ext_vector_type(8))) short bf16x8;
typedef __attribute__((ext_vector_type(4))) float f32x4;

__device__ __forceinline__ unsigned short f2bf(float f) {
    union { float f; unsigned int i; } u; u.f = f;
    unsigned int x = u.i;
    unsigned int r = (x + 0x7fffu + ((x >> 16) & 1u)) >> 16;  // RNE
    return (unsigned short)r;
}
__device__ __forceinline__ f32x4 mfma16(bf16x8 a, bf16x8 b, f32x4 c) {
    return __builtin_amdgcn_mfma_f32_16x16x32_bf16(a, b, c, 0, 0, 0);
}
__device__ __forceinline__ bf16x8 ldcvt8(const float* p) {
    float4 a = *(const float4*)p, b = *(const float4*)(p + 4);
    bf16x8 r;
    r[0] = (short)f2bf(a.x); r[1] = (short)f2bf(a.y); r[2] = (short)f2bf(a.z); r[3] = (short)f2bf(a.w);
    r[4] = (short)f2bf(b.x); r[5] = (short)f2bf(b.y); r[6] = (short)f2bf(b.z); r[7] = (short)f2bf(b.w);
    return r;
}

// system-scope write-through store (validated rounds 5/6): reaches the
// cross-XCD coherence point when vmcnt retires; no fence/wbl2/inv needed.
__device__ __forceinline__ void sysst(float* p, float v) {
    __hip_atomic_store(p, v, __ATOMIC_RELAXED, __HIP_MEMORY_SCOPE_SYSTEM);
}
__device__ __forceinline__ unsigned aload(unsigned* p) {
    return __hip_atomic_load(p, __ATOMIC_RELAXED, AGT);
}
__device__ __forceinline__ void aadd(unsigned* p, unsigned v) {
    __hip_atomic_fetch_add(p, v, __ATOMIC_RELAXED, AGT);
}
__device__ __forceinline__ void astore(unsigned* p, unsigned v) {
    __hip_atomic_store(p, v, __ATOMIC_RELAXED, AGT);
}
__device__ __forceinline__ void bar_reset(unsigned* bar) {
    for (int i = 1; i < 74; ++i) astore(bar + i * 32, 0u);   // arrive, done, dep, claims
}

struct KArgs {
    const float *x, *Wq, *bq, *Wk, *bk, *Wv, *bv, *Wo, *bo, *iq;
    const float *sW0, *sb0, *sW1, *sb1;
    float *kb, *h1, *dp;                    // f32 intermediates (sc1-written)
    float *vb, *qb, *hret, *pred, *dsil, *dh1p, *warm;
    unsigned *bar;
    float *out;
    Coefs cf;
};

// Two-tier grid barrier (round-6 proven, ~2 us each).
__device__ __forceinline__ void gsync(unsigned* bar, int w, int shard, bool& jan, int xcc) {
    __syncthreads();
    if (threadIdx.x == 0) {
        if (w == 0) {   // init-gate + janitor election (once per launch)
            while (aload(bar) != BAR_MAGIC) __builtin_amdgcn_s_sleep(8);
            unsigned prev = atomicCAS(bar + L_CLAIM(xcc), 0u, 1u);
            jan = (prev == 0);
        }
        aadd(bar + L_ARR(w, shard), 1u);
        if (jan) {
            for (;;) {
                unsigned s = 0;
                #pragma unroll
                for (int q = 0; q < 8; ++q) s += aload(bar + L_ARR(w, q));
                if (s == GRID_BLKS) break;
                __builtin_amdgcn_s_sleep(2);
            }
            astore(bar + L_DONE(w, xcc), 1u);
        }
        while (aload(bar + L_DONE(w, xcc)) == 0) __builtin_amdgcn_s_sleep(4);
        if (w == 3) {
            unsigned old = __hip_atomic_fetch_add(bar + L_DEP, 1u, __ATOMIC_RELAXED, AGT);
            if (old == GRID_BLKS - 1) bar_reset(bar);
        }
    }
    __syncthreads();
}

// ---- shared tile bodies (used by C2 and D) ----
__device__ __forceinline__ void nw1_tile(const KArgs& A, unsigned char* sbuf, int tile, int j) {
    float* a_t = (float*)sbuf;                 // [64][32]
    float* e_t = (float*)(sbuf + 8192);        // [64][64]
    const int b = tile / 144, rem = tile % 144;
    const int c0 = (rem / 12) * 32, h0 = (rem % 12) * 64;
    for (int i = j; i < TT * 32; i += 256) {
        int t = i >> 5, c = i & 31;
        a_t[t * 32 + c] = A.cf.ct[t] * A.dp[((size_t)(b * TT + t)) * CC + c0 + c];
    }
    for (int i = j; i < TT * 64; i += 256) {
        int t = i >> 6, h = i & 63;
        e_t[t * 64 + h] = A.h1[((size_t)(b * TT + t)) * HH + h0 + h];
    }
    __syncthreads();
    const int ci = j & 31, hb = (j >> 5) * 8;
    float acc[8] = {0, 0, 0, 0, 0, 0, 0, 0};
    for (int t = 0; t < TT; ++t) {
        float av = a_t[t * 32 + ci];
        #pragma unroll
        for (int m = 0; m < 8; ++m) acc[m] += av * e_t[t * 64 + hb + m];
    }
    const size_t idx = ((size_t)b * CC + c0 + ci) * HH + h0 + hb;
    const float4* w4 = (const float4*)(A.sW1 + idx);
    float4 wa = w4[0], wb = w4[1];
    float4 o0, o1;
    o0.x = A.cf.dfac * wa.x - acc[0]; o0.y = A.cf.dfac * wa.y - acc[1];
    o0.z = A.cf.dfac * wa.z - acc[2]; o0.w = A.cf.dfac * wa.w - acc[3];
    o1.x = A.cf.dfac * wb.x - acc[4]; o1.y = A.cf.dfac * wb.y - acc[5];
    o1.z = A.cf.dfac * wb.z - acc[6]; o1.w = A.cf.dfac * wb.w - acc[7];
    *(float4*)(A.out + O_NW1 + idx) = o0;
    *(float4*)(A.out + O_NW1 + idx + 4) = o1;
    if (h0 == 0 && j < 32) {
        float s = 0.f;
        for (int t = 0; t < TT; ++t) s += a_t[t * 32 + j];
        A.out[O_NB1 + b * CC + c0 + j] = A.cf.dfac * A.sb1[b * CC + c0 + j] - s;
    }
}

__device__ __forceinline__ void nw0_tile(const KArgs& A, unsigned char* sbuf, int tile, int j) {
    float* a_t = (float*)sbuf;                 // [64][32]
    float* e_t = (float*)(sbuf + 8192);        // [64][64]
    const int b = tile / 144, rem = tile % 144;
    const int h0 = (rem / 6) * 32, c0 = (rem % 6) * 64;
    for (int i = j; i < TT * 32; i += 256) {
        int t = i >> 5, hl = i & 31;
        a_t[t * 32 + hl] = A.dh1p[((size_t)(b * TT + t)) * HH + h0 + hl];
    }
    for (int i = j; i < TT * 64; i += 256) {
        int t = i >> 6, c = i & 63;
        e_t[t * 64 + c] = A.kb[((size_t)(b * TT + t)) * CC + c0 + c];
    }
    __syncthreads();
    const int hi = j & 31, cb = (j >> 5) * 8;
    float acc[8] = {0, 0, 0, 0, 0, 0, 0, 0};
    for (int t = 0; t < TT; ++t) {
        float av = a_t[t * 32 + hi];
        #pragma unroll
        for (int m = 0; m < 8; ++m) acc[m] += av * e_t[t * 64 + cb + m];
    }
    const size_t idx = ((size_t)b * HH + h0 + hi) * CC + c0 + cb;
    const float4* w4 = (const float4*)(A.sW0 + idx);
    float4 wa = w4[0], wb = w4[1];
    float4 o0, o1;
    o0.x = A.cf.dfac * wa.x - acc[0]; o0.y = A.cf.dfac * wa.y - acc[1];
    o0.z = A.cf.dfac * wa.z - acc[2]; o0.w = A.cf.dfac * wa.w - acc[3];
    o1.x = A.cf.dfac * wb.x - acc[4]; o1.y = A.cf.dfac * wb.y - acc[5];
    o1.z = A.cf.dfac * wb.z - acc[6]; o1.w = A.cf.dfac * wb.w - acc[7];
    *(float4*)(A.out + O_NW0 + idx) = o0;
    *(float4*)(A.out + O_NW0 + idx + 4) = o1;
    if (c0 == 0 && j < 32) {
        float s = 0.f;
        for (int t = 0; t < TT; ++t) s += a_t[t * 32 + j];
        A.out[O_NB0 + b * HH + h0 + j] = A.cf.dfac * A.sb0[b * HH + h0 + j] - s;
    }
}

// 5 phases / 4 barriers. GEMM phases use 16-wide warp tiles + unroll-4 K-loops
// for 4x the in-flight loads vs round 6 (latency -> throughput regime):
//   A : QKV, 102 blocks (384 m-warps [8 mf x 48 ntile] + 24 q-warps) + warm (210)
//   B : h1/dsil/hret, 120 blocks (480 warp-tiles)
//   C : dp/pred, 60 blocks (240 warp-tiles)
//   C2: dh1p (48) + out (48) + nW1 tiles 0..215
//   D : nW1 tiles 216..287 + 288 nW0 tiles
__global__ void __launch_bounds__(256, 2) fused(KArgs A) {
    __shared__ __align__(16) unsigned char sbuf[25344];
    const int blk = blockIdx.x, j = threadIdx.x;
    const int shard = blk & 7;
    bool jan = false;
    int xcc;
    asm volatile("s_getreg_b32 %0, hwreg(HW_REG_XCC_ID)" : "=s"(xcc));
    xcc &= 7;

    if (blk == 0 && j == 0) {
        if (aload(A.bar) != BAR_MAGIC) {
            bar_reset(A.bar);
            asm volatile("s_waitcnt vmcnt(0)" ::: "memory");
            astore(A.bar, BAR_MAGIC);
        }
    }

    const int wid = j >> 6, L = j & 63;
    const int lrow = L & 15, kq = (L >> 4) * 8, quad = L >> 4;

    // ---------------- Phase A: [x] @ [Wk|Wv]^T and iq @ Wq^T ----------------
    if (blk < 96) {                       // 384 m-warps = 8 mf x 48 ntile
        const int u = blk * 4 + wid;             // 0..383
        const int mf = u / 48, ntile = u % 48;   // mf 0..7, ntile 0..47
        const float* Arow = A.x + (size_t)(mf * 16 + lrow) * CC;
        const int n = ntile * 16 + lrow;         // 0..767
        const float* B0 = (n < CC) ? (A.Wk + (size_t)n * CC) : (A.Wv + (size_t)(n - CC) * CC);
        f32x4 acc0 = {0,0,0,0};
        #pragma unroll 4
        for (int s = 0; s < CC / 32; ++s) {
            int k = s * 32 + kq;
            acc0 = mfma16(ldcvt8(Arow + k), ldcvt8(B0 + k), acc0);
        }
        #pragma unroll
        for (int r = 0; r < 4; ++r) {
            int m = mf * 16 + quad * 4 + r;
            float v = acc0[r];
            if (n < CC) sysst(&A.kb[(size_t)m * CC + n], v + A.bk[n]);
            else        sysst(&A.vb[(size_t)m * CC + (n - CC)], v + A.bv[n - CC]);
        }
    } else if (blk < 102) {               // 24 q-warps: iq @ Wq^T (384 outputs)
        const int u = (blk - 96) * 4 + wid;      // 0..23
        const int n = u * 16 + lrow;             // 0..383
        const float* B0 = A.Wq + (size_t)n * CC;
        f32x4 acc0 = {0,0,0,0};
        #pragma unroll 4
        for (int s = 0; s < CC / 32; ++s) {
            int k = s * 32 + kq;
            acc0 = mfma16(ldcvt8(A.iq + k), ldcvt8(B0 + k), acc0);
        }
        if (quad == 0) sysst(&A.qb[n], acc0[0] + A.bq[n]);
    } else {
        // warm: stream FULL sW0 + sW1 + Wo (5.3 MB) into L3 for later phases
        int t = (blk - 102) * 256 + j;    // 210 blocks
        float acc = 0.f;
        for (int g = t; g < 331776; g += (GRID_BLKS - 102) * 256) {
            const float4* src; int off;
            if      (g < 147456) { src = (const float4*)A.sW0; off = g; }
            else if (g < 294912) { src = (const float4*)A.sW1; off = g - 147456; }
            else                 { src = (const float4*)A.Wo;  off = g - 294912; }
            float4 v = src[off];
            acc += v.x + v.y + v.z + v.w;
        }
        if (acc != acc) A.warm[0] = acc;
    }

    gsync(A.bar, 0, shard, jan, xcc);

    // ---------------- Phase B: [kb;q] @ sW0^T -> h1/dsil/hret ----------------
    if (blk < 120) {                      // 480 warps: b x (mf 0..4) x (ntile 0..47)
        const int b = blk / 60;
        const int u = (blk % 60) * 4 + wid;      // 0..239
        const int mf = u % 5, ntile = u / 5;     // ntile 0..47
        const float* Arow = (mf < 4) ? (A.kb + (size_t)(b * TT + mf * 16 + lrow) * CC) : A.qb;
        const int n = ntile * 16 + lrow;         // 0..767
        const float* B0 = A.sW0 + (size_t)(b * HH + n) * CC;
        f32x4 acc0 = {0,0,0,0};
        #pragma unroll 4
        for (int s = 0; s < CC / 32; ++s) {
            int k = s * 32 + kq;
            acc0 = mfma16(ldcvt8(Arow + k), ldcvt8(B0 + k), acc0);
        }
        float bias = A.sb0[b * HH + n];
        if (mf < 4) {
            #pragma unroll
            for (int r = 0; r < 4; ++r) {
                int t = mf * 16 + quad * 4 + r;
                float pre = acc0[r] + bias;
                float sig = 1.f / (1.f + expf(-pre));
                size_t idx = (size_t)(b * TT + t) * HH + n;
                sysst(&A.h1[idx], pre * sig);
                sysst(&A.dsil[idx], sig * (1.f + pre * (1.f - sig)));
            }
        } else if (quad == 0) {
            float pre = acc0[0] + bias;
            float sig = 1.f / (1.f + expf(-pre));
            sysst(&A.hret[b * HH + n], pre * sig);
        }
    }

    gsync(A.bar, 1, shard, jan, xcc);

    // ---------------- Phase C: [h1;hret] @ sW1^T -> dp/pred ----------------
    if (blk < 60) {                       // 240 warps: b x (mf 0..4) x (ntile 0..23)
        const int b = blk / 30;
        const int u = (blk % 30) * 4 + wid;      // 0..119
        const int mf = u % 5, ntile = u / 5;     // ntile 0..23
        const float* Arow = (mf < 4) ? (A.h1 + (size_t)(b * TT + mf * 16 + lrow) * HH)
                                     : (A.hret + (size_t)b * HH);
        const int n = ntile * 16 + lrow;         // 0..383
        const float* B0 = A.sW1 + (size_t)(b * CC + n) * HH;
        f32x4 acc0 = {0,0,0,0};
        #pragma unroll 4
        for (int s = 0; s < HH / 32; ++s) {
            int k = s * 32 + kq;
            acc0 = mfma16(ldcvt8(Arow + k), ldcvt8(B0 + k), acc0);
        }
        float bias = A.sb1[b * CC + n];
        if (mf < 4) {
            #pragma unroll
            for (int r = 0; r < 4; ++r) {
                int t = mf * 16 + quad * 4 + r;
                size_t idx = (size_t)(b * TT + t) * CC + n;
                sysst(&A.dp[idx], acc0[r] + bias - A.vb[idx]);
            }
        } else if (quad == 0) {
            sysst(&A.pred[b * CC + n], acc0[0] + bias);
        }
    }

    gsync(A.bar, 2, shard, jan, xcc);

    // ---------------- Phase C2: dh1p + out + 216 nW1 tiles ----------------
    if (blk < 48) {
        // dh1p[b,t,h] = ct[t] * dsil[b,t,h] * (dp @ sW1[b,:,h]) for h in [h0,h0+32)
        unsigned short* ldsT = (unsigned short*)sbuf;        // [384][33] bf16: [c][hl]
        const int b = blk / 24, h0 = (blk % 24) * 32;
        {
            const int hl = j & 31, cs = j >> 5;               // 8 c-rows per pass
            const float* base = A.sW1 + (size_t)b * CC * HH + h0 + hl;
            #pragma unroll 4
            for (int c = cs; c < CC; c += 8)
                ldsT[c * 33 + hl] = f2bf(base[(size_t)c * HH]);
        }
        __syncthreads();
        const float* Arow = A.dp + (size_t)(b * TT + wid * 16 + lrow) * CC;
        f32x4 acc0 = {0,0,0,0}, acc1 = {0,0,0,0};
        for (int s = 0; s < CC / 32; ++s) {
            int k = s * 32 + kq;
            bf16x8 a = ldcvt8(Arow + k);
            bf16x8 b0, b1;
            #pragma unroll
            for (int i = 0; i < 8; ++i) {
                b0[i] = (short)ldsT[(k + i) * 33 + lrow];
                b1[i] = (short)ldsT[(k + i) * 33 + 16 + lrow];
            }
            acc0 = mfma16(a, b0, acc0); acc1 = mfma16(a, b1, acc1);
        }
        #pragma unroll
        for (int ni = 0; ni < 2; ++ni) {
            f32x4 acc = ni == 0 ? acc0 : acc1;
            int hl = ni * 16 + lrow;
            #pragma unroll
            for (int r = 0; r < 4; ++r) {
                int t = wid * 16 + quad * 4 + r;
                float ds = A.dsil[(size_t)(b * TT + t) * HH + h0 + hl];
                sysst(&A.dh1p[(size_t)(b * TT + t) * HH + h0 + hl], A.cf.ct[t] * (acc[r] * ds));
            }
        }
    } else if (blk < 96) {                // out = pred@Wo^T + bo
        float* vecs = (float*)sbuf;
        float* part = (float*)(sbuf + 4096);
        const int rb = blk - 48;
        const int b = rb / 24, nt = rb % 24;
        if (j < CC / 4) ((float4*)vecs)[j] = ((const float4*)(A.pred + b * CC))[j];
        __syncthreads();
        const int nl = j & 15, ks = j >> 4;
        const int n = nt * 16 + nl;
        const float4* wr = (const float4*)(A.Wo + (size_t)n * CC + ks * 24);
        float s = 0.f;
        #pragma unroll
        for (int i = 0; i < 6; ++i) {
            float4 a4 = wr[i];
            const float* v = vecs + ks * 24 + i * 4;
            s += a4.x * v[0] + a4.y * v[1] + a4.z * v[2] + a4.w * v[3];
        }
        part[ks * 17 + nl] = s;
        __syncthreads();
        if (j < 16) {
            int n2 = nt * 16 + j;
            float acc = A.bo[n2];
            #pragma unroll
            for (int kk = 0; kk < 16; ++kk) acc += part[kk * 17 + j];
            A.out[O_OUT + b * CC + n2] = acc;
        }
    } else {                              // nW1 tiles 0..215
        nw1_tile(A, sbuf, blk - 96, j);
    }

    gsync(A.bar, 3, shard, jan, xcc);

    // ---------------- Phase D: 72 nW1 + 288 nW0 tiles (360), <=2 per block ----------------
    for (int pass = 0; pass < 2; ++pass) {
        int td = blk + pass * GRID_BLKS;
        if (td >= 360) break;
        __syncthreads();
        if (td < 72) nw1_tile(A, sbuf, 216 + td, j);
        else         nw0_tile(A, sbuf, td - 72, j);
    }
}

extern "C" void kernel_launch(void* const* d_in, const int* in_sizes, int n_in,
                              void* d_out, int out_size, void* d_ws, size_t ws_size,
                              hipStream_t stream) {
    KArgs a;
    a.x   = (const float*)d_in[0];
    a.Wq  = (const float*)d_in[1];
    a.bq  = (const float*)d_in[2];
    a.Wk  = (const float*)d_in[3];
    a.bk  = (const float*)d_in[4];
    a.Wv  = (const float*)d_in[5];
    a.bv  = (const float*)d_in[6];
    a.Wo  = (const float*)d_in[7];
    a.bo  = (const float*)d_in[8];
    a.iq  = (const float*)d_in[9];
    a.sW0 = (const float*)d_in[10];
    a.sb0 = (const float*)d_in[11];
    a.sW1 = (const float*)d_in[12];
    a.sb1 = (const float*)d_in[13];

    a.bar  = (unsigned*)d_ws;
    float* fw = (float*)d_ws + BAR_WORDS;
    a.qb   = fw;                 // 384
    a.hret = a.qb + 384;         // 1536
    a.pred = a.hret + 1536;      // 768
    a.vb   = a.pred + 768;       // 49152
    a.dsil = a.vb + 49152;       // 98304
    a.warm = a.dsil + 98304;     // 4
    a.kb   = a.warm + 4;         // 49152
    a.h1   = a.kb + 49152;       // 98304
    a.dp   = a.h1 + 98304;       // 49152
    a.dh1p = a.dp + 49152;       // 98304

    a.out = (float*)d_out;

    const double mom = 0.9, decay = 1.0 - 0.001, lr = 0.01;
    for (int s = 0; s < TT; ++s) {
        double sum = 0.0;
        for (int t = s; t < TT; ++t) sum += pow(decay, (double)(TT - 1 - t)) * pow(mom, (double)(t - s));
        a.cf.ct[s] = (float)(lr * (1.0 - mom) * sum);
    }
    a.cf.dfac = (float)pow(decay, (double)TT);

    fused<<<dim3(GRID_BLKS), dim3(256), 0, stream>>>(a);
}